// Round 7
// baseline (542.281 us; speedup 1.0000x reference)
//
#include <hip/hip_runtime.h>
#include <hip/hip_bf16.h>
#include <math.h>

constexpr int IN_C = 1024;
constexpr int HEADS = 4;
constexpr int F1 = 256;
constexpr int OUT_C = 64;
constexpr float NEG = 0.2f;

using bf16x8 = __attribute__((ext_vector_type(8))) short;
using f32x4 = __attribute__((ext_vector_type(4))) float;

__device__ __forceinline__ float leaky(float x) { return x > 0.f ? x : NEG * x; }

__device__ __forceinline__ unsigned short bf16bits(float v) {
  __hip_bfloat16 b = __float2bfloat16(v);
  return *reinterpret_cast<unsigned short*>(&b);
}
__device__ __forceinline__ float bf2f(unsigned short u) {
  union { unsigned u; float f; } c; c.u = (unsigned)u << 16; return c.f;
}

#define GLD_LDS16(g, l)                                                        \
  __builtin_amdgcn_global_load_lds(                                            \
      (const __attribute__((address_space(1))) void*)(g),                      \
      (__attribute__((address_space(3))) void*)(l), 16, 0, 0)

// ---- shuffle W[Nt*16][K] (f32) into MFMA B-fragment order (bf16) ----
// out[((kc*Nt + n16)*64 + lane)*8 + t] = W[n16*16 + (lane&15)][kc*32 + (lane>>4)*8 + t]
__global__ void shuf_w_kernel(const float* __restrict__ W,
                              unsigned short* __restrict__ out, int K, int Nt) {
  int idx = blockIdx.x * 256 + threadIdx.x;
  int total = (K >> 5) * Nt * 64;
  if (idx >= total) return;
  int lane = idx & 63;
  int rest = idx >> 6;
  int n16 = rest % Nt;
  int kc = rest / Nt;
  int row = n16 * 16 + (lane & 15);
  int colb = kc * 32 + (lane >> 4) * 8;
  const float* src = W + (size_t)row * K + colb;
  unsigned short tmp[8];
#pragma unroll
  for (int t = 0; t < 8; ++t) tmp[t] = bf16bits(src[t]);
  *(uint4*)(out + (size_t)idx * 8) = *(uint4*)tmp;
}

// ------- GEMM1: Hb[M,256] = X*W1^T, bf16 MFMA, B direct-from-global ----------------
// A: f32->bf16 double-buffered LDS (one barrier/tile). B: pre-shuffled fragments.
constexpr int LDTA = 72;

__global__ __launch_bounds__(256, 3) void gemm1_mfma(const float* __restrict__ X,
                                                     const unsigned short* __restrict__ Wsh,
                                                     unsigned short* __restrict__ Hb,
                                                     const float* __restrict__ a_src,
                                                     const float* __restrict__ a_dst,
                                                     float* __restrict__ as_out,
                                                     float* __restrict__ ad_out, int M) {
  __shared__ unsigned short As[2][64 * LDTA];  // 2 x 9 KB
  const int tid = threadIdx.x;
  const int wave = tid >> 6;
  const int lane = tid & 63;
  const int m15 = lane & 15;
  const int q = lane >> 4;
  const int bm = blockIdx.x * 64;

  f32x4 acc[4][4];
#pragma unroll
  for (int i = 0; i < 4; ++i)
#pragma unroll
    for (int j = 0; j < 4; ++j) acc[i][j] = (f32x4){0.f, 0.f, 0.f, 0.f};

  const int ar = tid >> 2;
  const int acg = (tid & 3) * 16;
  const int agr = (bm + ar < M) ? (bm + ar) : (M - 1);
  const float* aptr = X + (size_t)agr * IN_C + acg;
  // B fragment base: element (kc,j): + kc*8192 + j*512
  const unsigned short* bbase = Wsh + ((size_t)(wave * 4) * 64 + lane) * 8;

  // prologue: stage tile 0 into As[0]
  {
    float4 a0 = *(const float4*)(aptr + 0);
    float4 a1 = *(const float4*)(aptr + 4);
    float4 a2 = *(const float4*)(aptr + 8);
    float4 a3 = *(const float4*)(aptr + 12);
    union { uint4 u4[2]; __hip_bfloat162 h[8]; } pk;
    pk.h[0] = __float22bfloat162_rn(make_float2(a0.x, a0.y));
    pk.h[1] = __float22bfloat162_rn(make_float2(a0.z, a0.w));
    pk.h[2] = __float22bfloat162_rn(make_float2(a1.x, a1.y));
    pk.h[3] = __float22bfloat162_rn(make_float2(a1.z, a1.w));
    pk.h[4] = __float22bfloat162_rn(make_float2(a2.x, a2.y));
    pk.h[5] = __float22bfloat162_rn(make_float2(a2.z, a2.w));
    pk.h[6] = __float22bfloat162_rn(make_float2(a3.x, a3.y));
    pk.h[7] = __float22bfloat162_rn(make_float2(a3.z, a3.w));
    *(uint4*)&As[0][ar * LDTA + acg] = pk.u4[0];
    *(uint4*)&As[0][ar * LDTA + acg + 8] = pk.u4[1];
  }
  __syncthreads();

  int p = 0;
  for (int kt = 0; kt < IN_C; kt += 64) {
    const bool more = (kt + 64) < IN_C;
    float4 a0, a1, a2, a3;
    if (more) {  // prefetch next A tile (HBM) before compute
      a0 = *(const float4*)(aptr + kt + 64);
      a1 = *(const float4*)(aptr + kt + 68);
      a2 = *(const float4*)(aptr + kt + 72);
      a3 = *(const float4*)(aptr + kt + 76);
    }
    const int kc0 = kt >> 5;
#pragma unroll
    for (int k0 = 0; k0 < 64; k0 += 32) {
      const int kc = kc0 + (k0 >> 5);
      bf16x8 af[4], bfr[4];
#pragma unroll
      for (int j = 0; j < 4; ++j)
        bfr[j] = *(const bf16x8*)(bbase + (size_t)kc * 8192 + j * 512);
#pragma unroll
      for (int i = 0; i < 4; ++i)
        af[i] = *(const bf16x8*)&As[p][(i * 16 + m15) * LDTA + k0 + q * 8];
#pragma unroll
      for (int i = 0; i < 4; ++i)
#pragma unroll
        for (int j = 0; j < 4; ++j)
          acc[i][j] = __builtin_amdgcn_mfma_f32_16x16x32_bf16(af[i], bfr[j], acc[i][j], 0, 0, 0);
    }
    if (more) {
      union { uint4 u4[2]; __hip_bfloat162 h[8]; } pk;
      pk.h[0] = __float22bfloat162_rn(make_float2(a0.x, a0.y));
      pk.h[1] = __float22bfloat162_rn(make_float2(a0.z, a0.w));
      pk.h[2] = __float22bfloat162_rn(make_float2(a1.x, a1.y));
      pk.h[3] = __float22bfloat162_rn(make_float2(a1.z, a1.w));
      pk.h[4] = __float22bfloat162_rn(make_float2(a2.x, a2.y));
      pk.h[5] = __float22bfloat162_rn(make_float2(a2.z, a2.w));
      pk.h[6] = __float22bfloat162_rn(make_float2(a3.x, a3.y));
      pk.h[7] = __float22bfloat162_rn(make_float2(a3.z, a3.w));
      *(uint4*)&As[p ^ 1][ar * LDTA + acg] = pk.u4[0];
      *(uint4*)&As[p ^ 1][ar * LDTA + acg + 8] = pk.u4[1];
    }
    __syncthreads();
    p ^= 1;
  }

  float asf[4], adf[4];
#pragma unroll
  for (int j = 0; j < 4; ++j) {
    asf[j] = a_src[wave * 64 + j * 16 + m15];
    adf[j] = a_dst[wave * 64 + j * 16 + m15];
  }
#pragma unroll
  for (int i = 0; i < 4; ++i) {
#pragma unroll
    for (int r = 0; r < 4; ++r) {
      int row = bm + i * 16 + q * 4 + r;
      if (row < M) {
#pragma unroll
        for (int j = 0; j < 4; ++j)
          Hb[(size_t)row * F1 + wave * 64 + j * 16 + m15] = bf16bits(acc[i][j][r]);
      }
      float s = acc[i][0][r] * asf[0] + acc[i][1][r] * asf[1] +
                acc[i][2][r] * asf[2] + acc[i][3][r] * asf[3];
      float d = acc[i][0][r] * adf[0] + acc[i][1][r] * adf[1] +
                acc[i][2][r] * adf[2] + acc[i][3][r] * adf[3];
#pragma unroll
      for (int o = 1; o < 16; o <<= 1) {
        s += __shfl_xor(s, o, 64);
        d += __shfl_xor(d, o, 64);
      }
      if (m15 == 0 && row < M) {
        as_out[row * HEADS + wave] = s;
        ad_out[row * HEADS + wave] = d;
      }
    }
  }
}

// ------- GEMM2: H2[M,64] = Y(bf16)*W2^T + fused alpha; B direct-from-global --------
__global__ __launch_bounds__(256, 4) void gemm2_mfma(const unsigned short* __restrict__ Y,
                                                     const unsigned short* __restrict__ W2sh,
                                                     float* __restrict__ H2,
                                                     const float* __restrict__ a_src,
                                                     const float* __restrict__ a_dst,
                                                     float* __restrict__ as_out,
                                                     float* __restrict__ ad_out, int M) {
  __shared__ unsigned short As[64 * 64];  // 8 KB, xor-swizzled linear
  const int tid = threadIdx.x;
  const int wave = tid >> 6;
  const int lane = tid & 63;
  const int m15 = lane & 15;
  const int q = lane >> 4;
  const int bm = blockIdx.x * 64;

  f32x4 acc[4];
#pragma unroll
  for (int j = 0; j < 4; ++j) acc[j] = (f32x4){0.f, 0.f, 0.f, 0.f};
  const unsigned short* bbase = W2sh + ((size_t)lane) * 8;  // + kc*2048 + j*512

  for (int kt = 0; kt < F1; kt += 64) {
#pragma unroll
    for (int p = 0; p < 2; ++p) {
      int s = p * 256 + tid;
      int r = s >> 3;
      int cb = s & 7;
      int colo = (cb ^ (r & 7)) << 3;
      int gr = (bm + r < M) ? (bm + r) : (M - 1);
      GLD_LDS16(Y + (size_t)gr * F1 + kt + colo, &As[(p * 256 + wave * 64) * 8]);
    }
    __syncthreads();
#pragma unroll
    for (int k0 = 0; k0 < 64; k0 += 32) {
      const int kc = (kt + k0) >> 5;
      int ra = wave * 16 + m15;
      bf16x8 af = *(const bf16x8*)&As[ra * 64 + ((((k0 >> 3) + q) ^ (ra & 7)) << 3)];
      bf16x8 bfr[4];
#pragma unroll
      for (int j = 0; j < 4; ++j)
        bfr[j] = *(const bf16x8*)(bbase + (size_t)kc * 2048 + j * 512);
#pragma unroll
      for (int j = 0; j < 4; ++j)
        acc[j] = __builtin_amdgcn_mfma_f32_16x16x32_bf16(af, bfr[j], acc[j], 0, 0, 0);
    }
    __syncthreads();
  }
  float asf[4], adf[4];
#pragma unroll
  for (int j = 0; j < 4; ++j) {
    asf[j] = a_src[j * 16 + m15];
    adf[j] = a_dst[j * 16 + m15];
  }
#pragma unroll
  for (int r = 0; r < 4; ++r) {
    int row = bm + wave * 16 + q * 4 + r;
    if (row < M) {
#pragma unroll
      for (int j = 0; j < 4; ++j) H2[(size_t)row * OUT_C + j * 16 + m15] = acc[j][r];
    }
    float s = acc[0][r] * asf[0] + acc[1][r] * asf[1] + acc[2][r] * asf[2] + acc[3][r] * asf[3];
    float d = acc[0][r] * adf[0] + acc[1][r] * adf[1] + acc[2][r] * adf[2] + acc[3][r] * adf[3];
#pragma unroll
    for (int o = 1; o < 16; o <<= 1) {
      s += __shfl_xor(s, o, 64);
      d += __shfl_xor(d, o, 64);
    }
    if (m15 == 0 && row < M) {
      as_out[row] = s;
      ad_out[row] = d;
    }
  }
}

// ---------------- CSR build ----------------
__global__ void degree_kernel(const int* __restrict__ ei, int E, int N,
                              int* __restrict__ deg) {
  int e = blockIdx.x * blockDim.x + threadIdx.x;
  if (e >= E + N) return;
  int dst = (e < E) ? ei[E + e] : (e - E);
  atomicAdd(&deg[dst], 1);
}

__global__ __launch_bounds__(256) void scan_block_sums(const int* __restrict__ deg,
                                                       int* __restrict__ part, int n) {
  __shared__ int sm[256];
  int t = threadIdx.x;
  int i = blockIdx.x * 256 + t;
  sm[t] = (i < n) ? deg[i] : 0;
  __syncthreads();
  for (int off = 128; off > 0; off >>= 1) {
    if (t < off) sm[t] += sm[t + off];
    __syncthreads();
  }
  if (t == 0) part[blockIdx.x] = sm[0];
}

__global__ __launch_bounds__(256) void scan_partials(int* __restrict__ part, int P) {
  __shared__ int sm[256];
  int t = threadIdx.x;
  int v = (t < P) ? part[t] : 0;
  sm[t] = v;
  __syncthreads();
  for (int off = 1; off < 256; off <<= 1) {
    int u = (t >= off) ? sm[t - off] : 0;
    __syncthreads();
    sm[t] += u;
    __syncthreads();
  }
  if (t < P) part[t] = sm[t];
}

__global__ __launch_bounds__(256) void scan_final(const int* __restrict__ deg,
                                                  const int* __restrict__ part,
                                                  int* __restrict__ row_ptr, int n) {
  __shared__ int sm[256];
  int t = threadIdx.x;
  int i = blockIdx.x * 256 + t;
  sm[t] = (i < n) ? deg[i] : 0;
  __syncthreads();
  for (int off = 1; off < 256; off <<= 1) {
    int u = (t >= off) ? sm[t - off] : 0;
    __syncthreads();
    sm[t] += u;
    __syncthreads();
  }
  int base = blockIdx.x ? part[blockIdx.x - 1] : 0;
  if (i < n) row_ptr[i + 1] = base + sm[t];
  if (i == 0) row_ptr[0] = 0;
}

__global__ void scatter_kernel(const int* __restrict__ ei, int E, int N,
                               const int* __restrict__ row_ptr, int* __restrict__ fill,
                               int* __restrict__ col) {
  int e = blockIdx.x * blockDim.x + threadIdx.x;
  if (e >= E + N) return;
  int src, dst;
  if (e < E) { src = ei[e]; dst = ei[E + e]; }
  else       { src = e - E; dst = e - E; }
  int pos = row_ptr[dst] + atomicAdd(&fill[dst], 1);
  col[pos] = src;
}

// ------- layer-1 aggregate: wave/dst, two edges in flight (32-lane halves) ---------
__global__ __launch_bounds__(256) void agg1_kernel(const unsigned short* __restrict__ hb,
                                                   const float* __restrict__ as,
                                                   const float* __restrict__ ad,
                                                   const int* __restrict__ row_ptr,
                                                   const int* __restrict__ col,
                                                   const float* __restrict__ bias,
                                                   unsigned short* __restrict__ yb, int N) {
  int dst = (blockIdx.x * blockDim.x + threadIdx.x) >> 6;
  int lane = threadIdx.x & 63;
  if (dst >= N) return;
  const int s0 = row_ptr[dst], s1 = row_ptr[dst + 1];
  const int par = lane >> 5;
  const int cg = lane & 31;
  const int hh = cg >> 3;
  const float adl = ad[dst * 4 + hh];
  float acc[8];
#pragma unroll
  for (int k = 0; k < 8; ++k) acc[k] = 0.f;
  float den = 0.f;

  int i = s0 + par;
  for (; i + 2 < s1; i += 4) {
    int sA = col[i], sB = col[i + 2];
    float wA = __expf(leaky(as[sA * 4 + hh] + adl));
    float wB = __expf(leaky(as[sB * 4 + hh] + adl));
    uint4 hA = *(const uint4*)(hb + (size_t)sA * F1 + cg * 8);
    uint4 hB = *(const uint4*)(hb + (size_t)sB * F1 + cg * 8);
    den += wA + wB;
    const unsigned short* pa = (const unsigned short*)&hA;
    const unsigned short* pb = (const unsigned short*)&hB;
#pragma unroll
    for (int k = 0; k < 8; ++k) {
      acc[k] = fmaf(wA, bf2f(pa[k]), acc[k]);
      acc[k] = fmaf(wB, bf2f(pb[k]), acc[k]);
    }
  }
  for (; i < s1; i += 2) {
    int s = col[i];
    float w = __expf(leaky(as[s * 4 + hh] + adl));
    uint4 hv = *(const uint4*)(hb + (size_t)s * F1 + cg * 8);
    den += w;
    const unsigned short* p = (const unsigned short*)&hv;
#pragma unroll
    for (int k = 0; k < 8; ++k) acc[k] = fmaf(w, bf2f(p[k]), acc[k]);
  }
  den += __shfl_xor(den, 32, 64);
#pragma unroll
  for (int k = 0; k < 8; ++k) acc[k] += __shfl_xor(acc[k], 32, 64);

  if (par == 0) {
    const float iv = 1.f / den;
    float4 b0 = *(const float4*)(bias + cg * 8);
    float4 b1 = *(const float4*)(bias + cg * 8 + 4);
    float bv[8] = {b0.x, b0.y, b0.z, b0.w, b1.x, b1.y, b1.z, b1.w};
    ushort4 o[2];
    unsigned short* po = (unsigned short*)o;
#pragma unroll
    for (int k = 0; k < 8; ++k) {
      float v = acc[k] * iv + bv[k];
      v = v > 0.f ? v : (__expf(v) - 1.f);
      po[k] = bf16bits(v);
    }
    *(uint4*)(yb + (size_t)dst * F1 + cg * 8) = *(uint4*)o;
  }
}

// ------- layer-2 aggregate: wave/dst, two edges in flight; lane&31 -> 2 f32 ch -----
__global__ __launch_bounds__(256) void agg2_kernel(const float* __restrict__ h,
                                                   const float* __restrict__ as,
                                                   const float* __restrict__ ad,
                                                   const int* __restrict__ row_ptr,
                                                   const int* __restrict__ col,
                                                   const float* __restrict__ bias,
                                                   float* __restrict__ out, int N) {
  int dst = (blockIdx.x * blockDim.x + threadIdx.x) >> 6;
  int lane = threadIdx.x & 63;
  if (dst >= N) return;
  const int s0 = row_ptr[dst], s1 = row_ptr[dst + 1];
  const int par = lane >> 5;
  const int cg = lane & 31;
  const float adl = ad[dst];
  float a0 = 0.f, a1 = 0.f, den = 0.f;

  int i = s0 + par;
  for (; i + 2 < s1; i += 4) {
    int sA = col[i], sB = col[i + 2];
    float wA = __expf(leaky(as[sA] + adl));
    float wB = __expf(leaky(as[sB] + adl));
    float2 hA = *(const float2*)(h + (size_t)sA * OUT_C + cg * 2);
    float2 hB = *(const float2*)(h + (size_t)sB * OUT_C + cg * 2);
    den += wA + wB;
    a0 = fmaf(wA, hA.x, a0); a1 = fmaf(wA, hA.y, a1);
    a0 = fmaf(wB, hB.x, a0); a1 = fmaf(wB, hB.y, a1);
  }
  for (; i < s1; i += 2) {
    int s = col[i];
    float w = __expf(leaky(as[s] + adl));
    float2 hv = *(const float2*)(h + (size_t)s * OUT_C + cg * 2);
    den += w;
    a0 = fmaf(w, hv.x, a0); a1 = fmaf(w, hv.y, a1);
  }
  den += __shfl_xor(den, 32, 64);
  a0 += __shfl_xor(a0, 32, 64);
  a1 += __shfl_xor(a1, 32, 64);
  if (par == 0) {
    const float iv = 1.f / den;
    float2 bv = *(const float2*)(bias + cg * 2);
    float2 o = make_float2(a0 * iv + bv.x, a1 * iv + bv.y);
    *(float2*)(out + (size_t)dst * OUT_C + cg * 2) = o;
  }
}

extern "C" void kernel_launch(void* const* d_in, const int* in_sizes, int n_in,
                              void* d_out, int out_size, void* d_ws, size_t ws_size,
                              hipStream_t stream) {
  const float* x      = (const float*)d_in[0];
  const int*   ei     = (const int*)d_in[1];
  const float* W1     = (const float*)d_in[2];
  const float* a_src1 = (const float*)d_in[3];
  const float* a_dst1 = (const float*)d_in[4];
  const float* b1     = (const float*)d_in[5];
  const float* W2     = (const float*)d_in[6];
  const float* a_src2 = (const float*)d_in[7];
  const float* a_dst2 = (const float*)d_in[8];
  const float* b2     = (const float*)d_in[9];
  float* out = (float*)d_out;

  const int N = in_sizes[0] / IN_C;
  const int E = in_sizes[1] / 2;
  const int ET = E + N;

  char* ws = (char*)d_ws;
  size_t off = 0;
  auto alloc = [&](size_t bytes) -> void* {
    void* p = ws + off;
    off = (off + bytes + 255) & ~(size_t)255;
    return p;
  };
  unsigned short* h1b = (unsigned short*)alloc((size_t)N * F1 * 2);
  unsigned short* y1b = (unsigned short*)alloc((size_t)N * F1 * 2);
  float* h2      = (float*)alloc((size_t)N * OUT_C * 4);
  float* as1     = (float*)alloc((size_t)N * HEADS * 4);
  float* ad1     = (float*)alloc((size_t)N * HEADS * 4);
  float* as2     = (float*)alloc((size_t)N * 4);
  float* ad2     = (float*)alloc((size_t)N * 4);
  int*   deg     = (int*)alloc((size_t)N * 4);
  int*   row_ptr = (int*)alloc((size_t)(N + 1) * 4);
  int*   fill    = (int*)alloc((size_t)N * 4);
  int*   col     = (int*)alloc((size_t)ET * 4);
  int*   part    = (int*)alloc(1024 * 4);
  unsigned short* W1sh = (unsigned short*)alloc((size_t)F1 * IN_C * 2);
  unsigned short* W2sh = (unsigned short*)alloc((size_t)OUT_C * F1 * 2);
  (void)off; (void)ws_size; (void)n_in; (void)out_size;

  hipMemsetAsync(deg, 0, (size_t)N * 4, stream);
  hipMemsetAsync(fill, 0, (size_t)N * 4, stream);

  // W1/W2 -> bf16 MFMA fragment order
  shuf_w_kernel<<<(32 * 16 * 64 + 255) / 256, 256, 0, stream>>>(W1, W1sh, IN_C, 16);
  shuf_w_kernel<<<(8 * 4 * 64 + 255) / 256, 256, 0, stream>>>(W2, W2sh, F1, 4);

  const int P = (N + 255) / 256;
  degree_kernel<<<(ET + 255) / 256, 256, 0, stream>>>(ei, E, N, deg);
  scan_block_sums<<<P, 256, 0, stream>>>(deg, part, N);
  scan_partials<<<1, 256, 0, stream>>>(part, P);
  scan_final<<<P, 256, 0, stream>>>(deg, part, row_ptr, N);
  scatter_kernel<<<(ET + 255) / 256, 256, 0, stream>>>(ei, E, N, row_ptr, fill, col);

  const int NB4 = (N + 3) / 4;

  // ---- layer 1 ----
  gemm1_mfma<<<(N + 63) / 64, 256, 0, stream>>>(x, W1sh, h1b, a_src1, a_dst1, as1, ad1, N);
  agg1_kernel<<<NB4, 256, 0, stream>>>(h1b, as1, ad1, row_ptr, col, b1, y1b, N);

  // ---- layer 2 ----
  gemm2_mfma<<<(N + 63) / 64, 256, 0, stream>>>(y1b, W2sh, h2, a_src2, a_dst2, as2, ad2, N);
  agg2_kernel<<<NB4, 256, 0, stream>>>(h2, as2, ad2, row_ptr, col, b2, out, N);
}